// Round 4
// baseline (187.520 us; speedup 1.0000x reference)
//
#include <hip/hip_runtime.h>

// B=C=H=W=64, f32.
//   corr[b] = sum_chw map1[b]*map2[b];  corr /= ||corr||;  c = 1-corr;
//   out = map1 + map2 * c[b]
//
// Round 4: reduce kernel restructured to amortize the reduction tail.
// Evidence (r3): reduce pinned at 2.8 TB/s hot OR cold (latency/structure
// bound), while apply (same loads + stores, no reduce tail) exceeds
// 4.3 TB/s. Fix: 8x more streaming per block (1024 blocks x 16 f4-pairs
// per thread), one shfl/LDS tail per 256 KB instead of per 32 KB.

#define THREADS 256
#define NBATCH 64
#define RBPB 16               // reduce blocks per batch
#define ABPB 64               // apply blocks per batch
#define V4B 65536             // float4 per batch
#define RV4BLK 4096           // float4 per reduce block (16 iters * 256)
#define AV4BLK 1024           // float4 per apply block (4 iters * 256)

__global__ __launch_bounds__(THREADS, 4) void corr_reduce_kernel(
    const float4* __restrict__ m1, const float4* __restrict__ m2,
    float* __restrict__ partials) {
  const int b = blockIdx.y;
  const int base = b * V4B + blockIdx.x * RV4BLK + threadIdx.x;

  float acc0 = 0.f, acc1 = 0.f, acc2 = 0.f, acc3 = 0.f;
#pragma unroll
  for (int r = 0; r < 4; ++r) {
    float4 a[4], v[4];
    const int o = base + r * 4 * THREADS;
#pragma unroll
    for (int k = 0; k < 4; ++k) a[k] = m1[o + k * THREADS];
#pragma unroll
    for (int k = 0; k < 4; ++k) v[k] = m2[o + k * THREADS];
#pragma unroll
    for (int k = 0; k < 4; ++k) {
      acc0 = fmaf(a[k].x, v[k].x, acc0);
      acc1 = fmaf(a[k].y, v[k].y, acc1);
      acc2 = fmaf(a[k].z, v[k].z, acc2);
      acc3 = fmaf(a[k].w, v[k].w, acc3);
    }
  }
  float acc = (acc0 + acc1) + (acc2 + acc3);

#pragma unroll
  for (int off = 32; off > 0; off >>= 1) acc += __shfl_xor(acc, off);

  __shared__ float wsum[4];
  if ((threadIdx.x & 63) == 0) wsum[threadIdx.x >> 6] = acc;
  __syncthreads();
  if (threadIdx.x == 0)
    partials[b * RBPB + blockIdx.x] = (wsum[0] + wsum[1]) + (wsum[2] + wsum[3]);
}

__global__ __launch_bounds__(THREADS, 4) void corr_apply_kernel(
    const float4* __restrict__ m1, const float4* __restrict__ m2,
    const float4* __restrict__ partials4, float4* __restrict__ out) {
  const int b = blockIdx.y;
  const int base = b * V4B + blockIdx.x * AV4BLK + threadIdx.x;

  // streaming loads first...
  float4 a[4], v[4];
#pragma unroll
  for (int k = 0; k < 4; ++k) a[k] = m1[base + k * THREADS];
#pragma unroll
  for (int k = 0; k < 4; ++k) v[k] = m2[base + k * THREADS];

  // ...plus the corr prelude load, all in flight before the joint drain.
  // partials = 64 batches x 16 blocks = 1024 floats = 256 float4.
  // float4 index t holds floats [4t,4t+4), all of batch t/4.
  const float4 p = partials4[threadIdx.x];
  __builtin_amdgcn_sched_barrier(0);

  float s = (p.x + p.y) + (p.z + p.w);
  s += __shfl_xor(s, 1);
  s += __shfl_xor(s, 2);               // corr[t/4], replicated per 4-lane group

  __shared__ float csh[NBATCH];
  __shared__ float c_sh;
  if ((threadIdx.x & 3) == 0) csh[threadIdx.x >> 2] = s;
  __syncthreads();
  if (threadIdx.x < 64) {
    float cv = csh[threadIdx.x];
    float sq = cv * cv;
#pragma unroll
    for (int off = 32; off > 0; off >>= 1) sq += __shfl_xor(sq, off);
    if (threadIdx.x == 0) c_sh = 1.0f - csh[b] * rsqrtf(sq);
  }
  __syncthreads();
  const float c = c_sh;

#pragma unroll
  for (int k = 0; k < 4; ++k) {
    float4 o;
    o.x = fmaf(v[k].x, c, a[k].x);
    o.y = fmaf(v[k].y, c, a[k].y);
    o.z = fmaf(v[k].z, c, a[k].z);
    o.w = fmaf(v[k].w, c, a[k].w);
    out[base + k * THREADS] = o;
  }
}

extern "C" void kernel_launch(void* const* d_in, const int* in_sizes, int n_in,
                              void* d_out, int out_size, void* d_ws, size_t ws_size,
                              hipStream_t stream) {
  const float4* m1 = (const float4*)d_in[0];
  const float4* m2 = (const float4*)d_in[1];
  float* partials = (float*)d_ws;          // 1024 floats (4 KB) scratch
  float4* out = (float4*)d_out;

  dim3 rgrid(RBPB, NBATCH);
  dim3 agrid(ABPB, NBATCH);
  corr_reduce_kernel<<<rgrid, THREADS, 0, stream>>>(m1, m2, partials);
  corr_apply_kernel<<<agrid, THREADS, 0, stream>>>(m1, m2, (const float4*)partials, out);
}